// Round 11
// baseline (128.549 us; speedup 1.0000x reference)
//
#include <hip/hip_runtime.h>
#include <math.h>

// B=4, N=512, C=D=256, K=20, rows=2048
//
// ws layout (float offsets):
//   WtL [0, 65536)          W_l^T [c][d]
//   WtR [65536, 131072)
//   xT  [131072, 655360)    x transposed [c][row]  (256 x 2048)
//   XL  [1048576, +524288)  [row][d] row-major
//   XRt [1572864, +524288)  [b][d][j] d-major
//   Av  [2097152, +2048)    A_i = att.(W_l x_i + b_l)
//   Bv  [2099200, +2048)
//   ul  [2101248, +256)     W_l^T att
//   ur  [2101504, +256)
//   cs  [2101760, +2)       {att.b_l, att.b_r}
//
// out (float): [0,40960) index_i | [40960,81920) index_j | [81920,122880) attention

// async global->LDS DMA: per-lane gptr, WAVE-UNIFORM lds base; lane l lands at
// lds_base + 16*l  (16B x 64 lanes = 1 KB per inst)
#define GLD_LDS(gp, lp)                                                        \
    __builtin_amdgcn_global_load_lds(                                          \
        (const __attribute__((address_space(1))) float*)(gp),                  \
        (__attribute__((address_space(3))) float*)(lp), 16, 0, 0)

// u_l = W_l^T att, u_r = W_r^T att, cs = {att.bl, att.br}
__global__ __launch_bounds__(256) void k_uv(const float* __restrict__ Wl,
        const float* __restrict__ Wr, const float* __restrict__ bl,
        const float* __restrict__ br, const float* __restrict__ att,
        float* __restrict__ ul, float* __restrict__ ur, float* __restrict__ cs) {
    __shared__ float red[4];
    const int g = blockIdx.x, tid = threadIdx.x;
    float p;
    if (g < 512) {
        const int side = g >> 8, c = g & 255;
        const float* W = side ? Wr : Wl;
        p = att[tid] * W[(size_t)tid * 256 + c];
    } else {
        const float* bb = (g == 512) ? bl : br;
        p = att[tid] * bb[tid];
    }
#pragma unroll
    for (int off = 32; off; off >>= 1) p += __shfl_xor(p, off);
    if ((tid & 63) == 0) red[tid >> 6] = p;
    __syncthreads();
    if (tid == 0) {
        const float s = red[0] + red[1] + red[2] + red[3];
        if (g < 256) ul[g] = s;
        else if (g < 512) ur[g - 256] = s;
        else cs[g - 512] = s;
    }
}

// g<256: WtL row; g<512: WtR row; else xT column-scatter of x row g-512,
// fused with Av/Bv reduction (A_i = ul.x_i + cA) — zero extra global reads.
__global__ __launch_bounds__(256) void k_transpose(const float* __restrict__ x,
        const float* __restrict__ Wl, const float* __restrict__ Wr,
        const float* __restrict__ ul, const float* __restrict__ ur,
        const float* __restrict__ cs,
        float* __restrict__ WtL, float* __restrict__ WtR, float* __restrict__ xT,
        float* __restrict__ Av, float* __restrict__ Bv) {
    __shared__ float red[8];
    const int g = blockIdx.x, c = threadIdx.x;
    if (g < 256)      { WtL[c * 256 + g] = Wl[g * 256 + c]; return; }
    else if (g < 512) { WtR[c * 256 + (g - 256)] = Wr[(g - 256) * 256 + c]; return; }
    const int r = g - 512;                       // 0..2047
    const float xv = x[(size_t)r * 256 + c];
    xT[(size_t)c * 2048 + r] = xv;
    float p = xv * ul[c];
    float q = xv * ur[c];
#pragma unroll
    for (int off = 32; off; off >>= 1) {
        p += __shfl_xor(p, off);
        q += __shfl_xor(q, off);
    }
    if ((c & 63) == 0) { red[c >> 6] = p; red[4 + (c >> 6)] = q; }
    __syncthreads();
    if (c == 0) Av[r] = red[0] + red[1] + red[2] + red[3] + cs[0];
    if (c == 1) Bv[r] = red[4] + red[5] + red[6] + red[7] + cs[1];
}

// LDS-resident GEMM tile (R10 v5, byte-identical): grid 256 = side(2) x dq(4) x rb(32).
// wg computes 64 rows x 64 d for one side. W-tile + x-tile staged by DMA.
__global__ __launch_bounds__(256, 1) void k_proj(const float* __restrict__ xT,
        const float* __restrict__ WtL, const float* __restrict__ WtR,
        const float* __restrict__ bl, const float* __restrict__ br,
        float* __restrict__ XL, float* __restrict__ XRt) {
    __shared__ __align__(16) float xst[256 * 64];   // 64 KB [c][rr]
    __shared__ __align__(16) float wst[256 * 64];   // 64 KB [c][dd]
    const int tid = threadIdx.x;
    const int lane = tid & 63;
    const int wv = tid >> 6;           // 4 waves
    const int g = blockIdx.x;
    const int side = g & 1;
    const int dq = (g >> 1) & 3;
    const int rb = g >> 3;             // 0..31
    const int R = rb * 64;
    const int d0 = dq * 64;
    const int b = R >> 9;
    const float* __restrict__ W = side ? WtR : WtL;

#pragma unroll
    for (int n = 0; n < 16; ++n) {
        const int f4 = (n * 4 + wv) * 64 + lane;
        const int c = f4 >> 4, k4 = f4 & 15;
        GLD_LDS(xT + (size_t)c * 2048 + R + k4 * 4, &xst[(n * 4 + wv) * 256]);
        GLD_LDS(W + (size_t)c * 256 + d0 + k4 * 4, &wst[(n * 4 + wv) * 256]);
    }
    __syncthreads();                   // drains DMA (vmcnt 0)

    const int rt = tid & 15;           // r-quad
    const int dt = tid >> 4;           // d-quad 0..15
    float acc[4][4];
#pragma unroll
    for (int r = 0; r < 4; ++r)
#pragma unroll
        for (int k = 0; k < 4; ++k) acc[r][k] = 0.f;

    const float* xp = &xst[rt * 4];
    const float* wp = &wst[dt * 4];
#pragma unroll 8
    for (int c = 0; c < 256; ++c) {
        const float4 xv = *(const float4*)(xp + c * 64);   // 16 addr, 2-way: free
        const float4 wq = *(const float4*)(wp + c * 64);   // 4 addr x16 bcast: free
#define PROJ_R(r, XS)                              \
        acc[r][0] = fmaf(XS, wq.x, acc[r][0]);     \
        acc[r][1] = fmaf(XS, wq.y, acc[r][1]);     \
        acc[r][2] = fmaf(XS, wq.z, acc[r][2]);     \
        acc[r][3] = fmaf(XS, wq.w, acc[r][3]);
        PROJ_R(0, xv.x)
        PROJ_R(1, xv.y)
        PROJ_R(2, xv.z)
        PROJ_R(3, xv.w)
#undef PROJ_R
    }

    const float4 bias = *(const float4*)&(side ? br : bl)[d0 + dt * 4];
    if (side == 0) {
#pragma unroll
        for (int r = 0; r < 4; ++r) {
            *(float4*)&XL[(size_t)(R + rt * 4 + r) * 256 + d0 + dt * 4] =
                make_float4(acc[r][0] + bias.x, acc[r][1] + bias.y,
                            acc[r][2] + bias.z, acc[r][3] + bias.w);
        }
    } else {
        const int jr = (R & 511) + rt * 4;
#pragma unroll
        for (int k = 0; k < 4; ++k) {
            const int d = d0 + dt * 4 + k;
            const float bk = k == 0 ? bias.x : k == 1 ? bias.y : k == 2 ? bias.z : bias.w;
            *(float4*)&XRt[((size_t)(b * 256 + d)) * 512 + jr] =
                make_float4(acc[0][k] + bk, acc[1][k] + bk,
                            acc[2][k] + bk, acc[3][k] + bk);
        }
    }
}

// Fused pair + top-k + softmax (R7 version, byte-identical — best known ~39 us).
// 256 wgs x 512 thr; thread: jc = tid&127 -> j-quad, h = tid>>7 -> d-quarter, ALL 8 i.
__global__ __launch_bounds__(512, 2) void k_pair_topk(const float* __restrict__ XL,
        const float* __restrict__ XRt, const float* __restrict__ Av,
        const float* __restrict__ Bv, const float* __restrict__ att,
        float* __restrict__ out) {
    __shared__ __align__(16) float xls[8 * 256];     // 8 KB
    __shared__ __align__(16) float atts[256];        // 1 KB
    __shared__ __align__(16) float mrg[3 * 4096];    // 48 KB: h=1..3 partials [i][j]
    __shared__ __align__(16) float alph[8 * 512];    // 16 KB
    const int tid = threadIdx.x;       // 0..511
    const int jc = tid & 127;          // j-quad index
    const int h = tid >> 7;            // d-quarter 0..3 (wave-uniform)
    const int g = blockIdx.x;          // 0..255
    const int R = g * 8, b = R >> 9;

    ((float4*)xls)[tid] = ((const float4*)(XL + (size_t)R * 256))[tid];
    if (tid < 64) ((float4*)atts)[tid] = ((const float4*)att)[tid];
    __syncthreads();

    const int dbase = h * 64;
    const float* __restrict__ xrp = XRt + (size_t)b * 131072 + (size_t)dbase * 512 + jc * 4;

    float acc[8][4];
#pragma unroll
    for (int i = 0; i < 8; ++i)
#pragma unroll
        for (int c = 0; c < 4; ++c) acc[i][c] = 0.f;

    float4 bufA[8], bufB[8];
#pragma unroll
    for (int dd = 0; dd < 8; ++dd) bufA[dd] = *(const float4*)(xrp + (size_t)dd * 512);

#pragma unroll
    for (int ch = 0; ch < 8; ++ch) {
        const float4* cur = (ch & 1) ? bufB : bufA;   // static under full unroll
        float4* nxt = (ch & 1) ? bufA : bufB;
        if (ch < 7) {
            const float* p = xrp + (size_t)(ch + 1) * 8 * 512;
#pragma unroll
            for (int dd = 0; dd < 8; ++dd) nxt[dd] = *(const float4*)(p + (size_t)dd * 512);
        }
        const int d0 = dbase + ch * 8;
        const float4 at0 = *(const float4*)&atts[d0];      // LDS b128 broadcast
        const float4 at1 = *(const float4*)&atts[d0 + 4];
#pragma unroll
        for (int i = 0; i < 8; ++i) {
            const float4 xa = *(const float4*)&xls[i * 256 + d0];
            const float4 xb = *(const float4*)&xls[i * 256 + d0 + 4];
#define PSTEP(XLC, ATC, XR4)                                       \
            acc[i][0] = fmaf(ATC, fabsf(XLC + XR4.x), acc[i][0]);   \
            acc[i][1] = fmaf(ATC, fabsf(XLC + XR4.y), acc[i][1]);   \
            acc[i][2] = fmaf(ATC, fabsf(XLC + XR4.z), acc[i][2]);   \
            acc[i][3] = fmaf(ATC, fabsf(XLC + XR4.w), acc[i][3]);
            PSTEP(xa.x, at0.x, cur[0])
            PSTEP(xa.y, at0.y, cur[1])
            PSTEP(xa.z, at0.z, cur[2])
            PSTEP(xa.w, at0.w, cur[3])
            PSTEP(xb.x, at1.x, cur[4])
            PSTEP(xb.y, at1.y, cur[5])
            PSTEP(xb.z, at1.z, cur[6])
            PSTEP(xb.w, at1.w, cur[7])
#undef PSTEP
        }
    }

    // merge d-quarters: h=1..3 dump partials, h=0 finishes
    if (h) {
        float* m = &mrg[(h - 1) * 4096];
#pragma unroll
        for (int i = 0; i < 8; ++i)
            *(float4*)&m[i * 512 + jc * 4] =
                make_float4(acc[i][0], acc[i][1], acc[i][2], acc[i][3]);
    }
    __syncthreads();
    if (h == 0) {
        const float4 Bj = *(const float4*)&Bv[b * 512 + jc * 4];
#pragma unroll
        for (int i = 0; i < 8; ++i) {
            const float Ai = Av[R + i];
            const float4 m0 = *(const float4*)&mrg[i * 512 + jc * 4];
            const float4 m1 = *(const float4*)&mrg[4096 + i * 512 + jc * 4];
            const float4 m2 = *(const float4*)&mrg[8192 + i * 512 + jc * 4];
            float a0 = fmaf(0.4f, acc[i][0] + m0.x + m1.x + m2.x, 0.6f * (Ai + Bj.x));
            float a1 = fmaf(0.4f, acc[i][1] + m0.y + m1.y + m2.y, 0.6f * (Ai + Bj.y));
            float a2 = fmaf(0.4f, acc[i][2] + m0.z + m1.z + m2.z, 0.6f * (Ai + Bj.z));
            float a3 = fmaf(0.4f, acc[i][3] + m0.w + m1.w + m2.w, 0.6f * (Ai + Bj.w));
            if (!isfinite(a0)) a0 = 0.f;   // nan_to_num
            if (!isfinite(a1)) a1 = 0.f;
            if (!isfinite(a2)) a2 = 0.f;
            if (!isfinite(a3)) a3 = 0.f;
            *(float4*)&alph[i * 512 + jc * 4] = make_float4(a0, a1, a2, a3);
        }
    }
    __syncthreads();

    // top-20 + softmax: wave w handles row w (8 waves, 8 rows)
    const int lane = tid & 63;
    const int i = tid >> 6;
    const float* ar = &alph[i * 512];
    const float4 u0 = *(const float4*)&ar[lane * 8];
    const float4 u1 = *(const float4*)&ar[lane * 8 + 4];
    float v[8] = {u0.x, u0.y, u0.z, u0.w, u1.x, u1.y, u1.z, u1.w};  // j = lane*8+t

    float myval = 0.f, mmax = 0.f;
    int myidx = 0;
    for (int sel = 0; sel < 20; ++sel) {
        float bv = v[0]; int bt = 0;
#pragma unroll
        for (int t = 1; t < 8; ++t) { if (v[t] > bv) { bv = v[t]; bt = t; } }
        int bj = lane * 8 + bt;
#pragma unroll
        for (int off = 32; off; off >>= 1) {   // butterfly argmax, lower j wins ties
            const float ov = __shfl_xor(bv, off);
            const int   oj = __shfl_xor(bj, off);
            if (ov > bv || (ov == bv && oj < bj)) { bv = ov; bj = oj; }
        }
        if (sel == 0) mmax = bv;
        if (lane == sel) { myval = bv; myidx = bj; }
        if ((bj >> 3) == lane) {
            const int bt2 = bj & 7;
#pragma unroll
            for (int t = 0; t < 8; ++t) if (t == bt2) v[t] = -INFINITY;
        }
    }
    const float e = (lane < 20) ? expf(myval - mmax) : 0.f;
    float s = e;
#pragma unroll
    for (int off = 32; off; off >>= 1) s += __shfl_xor(s, off);
    if (lane < 20) {
        const int row = R + i;
        const int base = row * 20 + lane;
        out[base] = (float)row;                        // index_i
        out[40960 + base] = (float)(b * 512 + myidx);  // index_j
        out[81920 + base] = e / s;                     // attention
    }
}

extern "C" void kernel_launch(void* const* d_in, const int* in_sizes, int n_in,
                              void* d_out, int out_size, void* d_ws, size_t ws_size,
                              hipStream_t stream) {
    const float* x   = (const float*)d_in[0];
    const float* Wl  = (const float*)d_in[3];
    const float* bl  = (const float*)d_in[4];
    const float* Wr  = (const float*)d_in[5];
    const float* br  = (const float*)d_in[6];
    const float* att = (const float*)d_in[7];

    float* ws  = (float*)d_ws;
    float* WtL = ws;
    float* WtR = ws + 65536;
    float* xT  = ws + 131072;
    float* XL  = ws + 1048576;
    float* XRt = ws + 1572864;
    float* Av  = ws + 2097152;
    float* Bv  = ws + 2099200;
    float* ul  = ws + 2101248;
    float* ur  = ws + 2101504;
    float* cs  = ws + 2101760;
    float* out = (float*)d_out;

    k_uv<<<dim3(514), dim3(256), 0, stream>>>(Wl, Wr, bl, br, att, ul, ur, cs);
    k_transpose<<<dim3(2560), dim3(256), 0, stream>>>(x, Wl, Wr, ul, ur, cs,
                                                      WtL, WtR, xT, Av, Bv);
    k_proj<<<dim3(256), dim3(256), 0, stream>>>(xT, WtL, WtR, bl, br, XL, XRt);
    k_pair_topk<<<dim3(256), dim3(512), 0, stream>>>(XL, XRt, Av, Bv, att, out);
}